// Round 1
// 973.493 us; speedup vs baseline: 1.1780x; 1.1780x over previous
//
#include <hip/hip_runtime.h>
#include <hip/hip_bf16.h>

#define SEQ 2048
#define BATCH 2
#define NH 16
#define DK 64
#define DM 1024

typedef __bf16 bf16;
typedef __bf16 bf16x8 __attribute__((ext_vector_type(8)));
typedef float f32x4 __attribute__((ext_vector_type(4)));
typedef short s16x4 __attribute__((ext_vector_type(4)));

#define MFMA16(a,b,c) __builtin_amdgcn_mfma_f32_16x16x32_bf16(a,b,c,0,0,0)
#define NEG_BIG (-1.0e30f)

// async global->LDS, 16B per lane. LDS dest must be linear (base + lane*16).
#define GLL16(gsrc, ldst) __builtin_amdgcn_global_load_lds( \
    (const __attribute__((address_space(1))) void*)(gsrc), \
    (__attribute__((address_space(3))) void*)(ldst), 16, 0, 0)

__device__ __forceinline__ bf16x8 ld8(const bf16* p){ return *(const bf16x8*)p; }

// Read an 8-f32 MFMA fragment from a chunk-swizzled [128][32] f32 LDS tile,
// cvt to bf16. Swizzle: LDS[row][ch] holds global chunk (ch ^ (row&7)); the
// XOR spreads the 16 same-column lanes across all 8 b128 slots (b128 floor).
__device__ __forceinline__ bf16x8 frag_f32lds(const float* Ls, int row, int lq){
    int c0 = ((lq<<1)    ) ^ (row&7);
    int c1 = ((lq<<1) | 1) ^ (row&7);
    const float* p = Ls + row*32;
    f32x4 a = *(const f32x4*)(p + c0*4);
    f32x4 b = *(const f32x4*)(p + c1*4);
    bf16x8 r;
    #pragma unroll
    for (int i=0;i<4;i++){ r[i] = (bf16)a[i]; r[i+4] = (bf16)b[i]; }
    return r;
}

// Read an 8-bf16 fragment from a chunk-swizzled [128][32] bf16 LDS tile.
__device__ __forceinline__ bf16x8 frag_bf16lds(const bf16* Ls, int row, int lq){
    int c = lq ^ (row&3);
    return *(const bf16x8*)((const char*)Ls + row*64 + c*16);
}

// ---------------------------------------------------------------------------
// QKV projection: C = X @ W^T, X [4096x1024] f32, W [1024x1024] f32 (both
// K-contiguous). m97 structure: 128x128 tile, BK=32, 4 waves (2x2 of 64x64),
// global_load_lds staging of both f32 tiles, swizzled ds_read_b128 + cvt.
// z=0 -> q_s [B,H,S,dk]; z=1 -> k_s; z=2 -> vt_s [B,H,dk,S]  (bf16)
// ---------------------------------------------------------------------------
__global__ __launch_bounds__(256) void qkv_proj_kernel(
    const float* __restrict__ Qin, const float* __restrict__ Kin, const float* __restrict__ Vin,
    const float* __restrict__ Wq,  const float* __restrict__ Wk,  const float* __restrict__ Wv,
    bf16* __restrict__ q_s, bf16* __restrict__ k_s, bf16* __restrict__ vt_s)
{
    __shared__ __align__(16) float As[128*32];
    __shared__ __align__(16) float Bs[128*32];
    const int z = blockIdx.z;
    const float* X = (z==0) ? Qin : (z==1) ? Kin : Vin;
    const float* W = (z==0) ? Wq  : (z==1) ? Wk  : Wv;
    bf16* out      = (z==0) ? q_s : (z==1) ? k_s : vt_s;

    const int tid  = threadIdx.x;
    const int lane = tid & 63;
    const int w    = tid >> 6;
    const int lr = lane & 15, lq = lane >> 4;
    const int mt  = (w>>1)*64;                 // wave sub-tile bases (in tile)
    const int nt0 = (w&1)*64;
    const int m0 = blockIdx.y*128;
    const int n0 = blockIdx.x*128;

    f32x4 acc[4][4] = {};
    for (int k0 = 0; k0 < DM; k0 += 32) {
        if (k0) __syncthreads();               // prev compute done before overwrite
        #pragma unroll
        for (int i=0;i<4;i++){
            int ci  = i*256 + tid;             // 16B chunk index, 0..1023
            int row = ci >> 3, ch = ci & 7;    // tile row, LDS chunk-in-row
            int gc  = (ch ^ (row&7)) * 4;      // inverse-swizzled source (f32 units)
            GLL16(X + (size_t)(m0+row)*DM + k0 + gc, (char*)As + ci*16);
            GLL16(W + (size_t)(n0+row)*DM + k0 + gc, (char*)Bs + ci*16);
        }
        __syncthreads();                       // drains vmcnt -> tiles ready
        bf16x8 af[4], bfr[4];
        #pragma unroll
        for (int mi=0;mi<4;mi++) af[mi]  = frag_f32lds(As, mt  + mi*16 + lr, lq);
        #pragma unroll
        for (int ni=0;ni<4;ni++) bfr[ni] = frag_f32lds(Bs, nt0 + ni*16 + lr, lq);
        #pragma unroll
        for (int mi=0;mi<4;mi++)
            #pragma unroll
            for (int ni=0;ni<4;ni++)
                acc[mi][ni] = MFMA16(af[mi], bfr[ni], acc[mi][ni]);
    }

    if (z == 2) {
        // V transposed: pack the 4 consecutive-token values into one 8B store
        #pragma unroll
        for (int mi=0;mi<4;mi++)
        #pragma unroll
        for (int ni=0;ni<4;ni++){
            int row = m0 + mt + mi*16 + lq*4;          // first of 4 tokens
            int col = n0 + nt0 + ni*16 + lr;
            int b = row >> 11, s = row & (SEQ-1);
            int h = col >> 6,  dd = col & 63;
            bf16 pk[4];
            #pragma unroll
            for (int r=0;r<4;r++) pk[r] = (bf16)acc[mi][ni][r];
            *(s16x4*)&out[((size_t)((b*NH + h)*DK + dd))*SEQ + s] = *(const s16x4*)pk;
        }
    } else {
        #pragma unroll
        for (int mi=0;mi<4;mi++)
        #pragma unroll
        for (int ni=0;ni<4;ni++)
        #pragma unroll
        for (int r=0;r<4;r++) {
            int row = m0 + mt + mi*16 + lq*4 + r;      // token index (b*S + s)
            int col = n0 + nt0 + ni*16 + lr;           // feature (h*64 + d)
            int b = row >> 11, s = row & (SEQ-1);
            int h = col >> 6,  dd = col & 63;
            out[((size_t)(b*NH + h))*SEQ*DK + (size_t)s*DK + dd] = (bf16)acc[mi][ni][r];
        }
    }
}

// ---------------------------------------------------------------------------
// Attention: one block = 32 queries of one (b,h), 2 waves x 16 queries.
// Grid 64x32 = 2048 blocks -> 8-12 blocks/CU resident (vs 4 before).
// Max-free two-pass softmax (scores bounded, exp cannot overflow f32).
// Pass 1: l = sum(exp(s)). Pass 2: p = exp(s)/l -> direct f32 dword stores
// (C-layout is 16-lane/64B coalesced) + bf16 P via LDS for the PV MFMA.
// ---------------------------------------------------------------------------
__device__ __forceinline__ void compute_scores(
    const bf16* __restrict__ kp, const bf16x8* qf,
    int kt, int ktmax, int qw0, int lr, int lq, f32x4* s)
{
    const f32x4 z4 = {0.f,0.f,0.f,0.f};
    s[0]=z4; s[1]=z4; s[2]=z4; s[3]=z4;
    #pragma unroll
    for (int ks=0; ks<2; ks++) {
        #pragma unroll
        for (int nt=0; nt<4; nt++) {
            bf16x8 kf = ld8(kp + (size_t)(kt*64 + nt*16 + lr)*DK + ks*32 + lq*8);
            s[nt] = MFMA16(qf[ks], kf, s[nt]);
        }
    }
    #pragma unroll
    for (int nt=0; nt<4; nt++)
        #pragma unroll
        for (int r=0; r<4; r++) {
            float v = s[nt][r]*0.125f;                   // 1/sqrt(64)
            // causal mask only possible in the wave's final tile
            if (kt==ktmax && (kt*64 + nt*16 + lr) > (qw0 + lq*4 + r))
                v = NEG_BIG;
            s[nt][r] = v;
        }
}

__global__ __launch_bounds__(128,4) void attn_kernel(
    const bf16* __restrict__ q_s, const bf16* __restrict__ k_s,
    const bf16* __restrict__ vt_s,
    float* __restrict__ attn_out, bf16* __restrict__ ao)
{
    __shared__ __align__(16) bf16 P[2][16][72];   // per-wave bf16 P (MFMA A reads)
    const int bh = blockIdx.y;
    const int lane = threadIdx.x & 63, w = threadIdx.x >> 6;
    const int lr = lane & 15, lq = lane >> 4;
    const bf16* qp = q_s  + (size_t)bh*SEQ*DK;
    const bf16* kp = k_s  + (size_t)bh*SEQ*DK;
    const bf16* vp = vt_s + (size_t)bh*DK*SEQ;
    float* ab = attn_out + (size_t)bh*SEQ*SEQ;
    const int qw0   = blockIdx.x*32 + w*16;       // this wave's first query
    const int ktmax = (qw0 + 15) >> 6;            // last needed 64-key tile

    bf16x8 qf[2];
    qf[0] = ld8(qp + (size_t)(qw0+lr)*DK + lq*8);
    qf[1] = ld8(qp + (size_t)(qw0+lr)*DK + 32 + lq*8);

    // ---- pass 1: row sums of exp(s) (no max tracking; scores bounded) ----
    float l_r[4] = {0.f,0.f,0.f,0.f};
    for (int kt=0; kt<=ktmax; kt++) {
        f32x4 s[4];
        compute_scores(kp, qf, kt, ktmax, qw0, lr, lq, s);
        #pragma unroll
        for (int r=0;r<4;r++){
            float sm = __expf(s[0][r])+__expf(s[1][r])
                     + __expf(s[2][r])+__expf(s[3][r]);
            sm += __shfl_xor(sm,1); sm += __shfl_xor(sm,2);
            sm += __shfl_xor(sm,4); sm += __shfl_xor(sm,8);
            l_r[r] += sm;
        }
    }
    float inv_l[4];
    #pragma unroll
    for (int r=0;r<4;r++) inv_l[r] = 1.0f / l_r[r];   // l >= exp(s_ii) > 0

    // ---- pass 2: attn stores (direct, f32) + O accumulate ----
    f32x4 o[4] = {};
    for (int kt=0; kt<=ktmax; kt++) {
        f32x4 s[4];
        compute_scores(kp, qf, kt, ktmax, qw0, lr, lq, s);
        #pragma unroll
        for (int nt=0;nt<4;nt++)
            #pragma unroll
            for (int r=0;r<4;r++){
                float p = __expf(s[nt][r]) * inv_l[r];
                // C-layout store: fixed (nt,r) -> 4 rows x 16 consecutive cols (64B)
                ab[(size_t)(qw0 + lq*4 + r)*SEQ + kt*64 + nt*16 + lr] = p;
                P[w][lq*4+r][nt*16+lr] = (bf16)p;
            }
        __asm__ __volatile__("" ::: "memory");   // keep LDS writes before reads
        #pragma unroll
        for (int ks=0;ks<2;ks++){
            bf16x8 pf = *(const bf16x8*)(&P[w][lr][ks*32 + lq*8]);  // A-layout
            #pragma unroll
            for (int nt=0;nt<4;nt++){
                bf16x8 vf = ld8(vp + (size_t)(nt*16+lr)*SEQ + kt*64 + ks*32 + lq*8);
                o[nt] = MFMA16(pf, vf, o[nt]);
            }
        }
    }

    const int b = bh >> 4, h = bh & 15;
    #pragma unroll
    for (int nt=0;nt<4;nt++)
        #pragma unroll
        for (int r=0;r<4;r++){
            int qrow = qw0 + lq*4 + r;
            ao[(size_t)(b*SEQ + qrow)*DM + h*64 + nt*16 + lr] = (bf16)o[nt][r];
        }

    // ---- zero-fill this wave's strictly-upper attn columns ----
    int cstart = (ktmax+1)*64;
    if (cstart < SEQ) {
        const f32x4 z4 = {0.f,0.f,0.f,0.f};
        float* rp = ab + (size_t)(qw0 + (lane>>2))*SEQ;   // 4 lanes per row
        for (int c4 = (cstart>>2) + (lane&3); c4 < (SEQ>>2); c4 += 4)
            *(f32x4*)(rp + c4*4) = z4;
    }
}

// ---------------------------------------------------------------------------
// Output projection: out = AO @ Wo^T + bo. AO bf16 [4096x1024], Wo f32,
// out f32. Same staged structure; A staged as bf16 (4 chunks/row, &3 swizzle).
// ---------------------------------------------------------------------------
__global__ __launch_bounds__(256) void out_proj_kernel(
    const bf16* __restrict__ Xa, const float* __restrict__ Wo,
    const float* __restrict__ bo, float* __restrict__ out)
{
    __shared__ __align__(16) bf16  Asb[128*32];
    __shared__ __align__(16) float Bs [128*32];
    const int tid  = threadIdx.x;
    const int lane = tid & 63;
    const int w    = tid >> 6;
    const int lr = lane & 15, lq = lane >> 4;
    const int mt  = (w>>1)*64;
    const int nt0 = (w&1)*64;
    const int m0 = blockIdx.y*128;
    const int n0 = blockIdx.x*128;

    f32x4 acc[4][4] = {};
    for (int k0 = 0; k0 < DM; k0 += 32) {
        if (k0) __syncthreads();
        #pragma unroll
        for (int i=0;i<2;i++){                  // A: 8KB bf16 = 2 rounds
            int ci  = i*256 + tid;
            int row = ci >> 2, ch = ci & 3;
            GLL16(Xa + (size_t)(m0+row)*DM + k0 + ((ch ^ (row&3))<<3),
                  (char*)Asb + ci*16);
        }
        #pragma unroll
        for (int i=0;i<4;i++){                  // B: 16KB f32 = 4 rounds
            int ci  = i*256 + tid;
            int row = ci >> 3, ch = ci & 7;
            GLL16(Wo + (size_t)(n0+row)*DM + k0 + ((ch ^ (row&7))<<2),
                  (char*)Bs + ci*16);
        }
        __syncthreads();
        bf16x8 af[4], bfr[4];
        #pragma unroll
        for (int mi=0;mi<4;mi++) af[mi]  = frag_bf16lds(Asb, mt  + mi*16 + lr, lq);
        #pragma unroll
        for (int ni=0;ni<4;ni++) bfr[ni] = frag_f32lds (Bs,  nt0 + ni*16 + lr, lq);
        #pragma unroll
        for (int mi=0;mi<4;mi++)
            #pragma unroll
            for (int ni=0;ni<4;ni++)
                acc[mi][ni] = MFMA16(af[mi], bfr[ni], acc[mi][ni]);
    }
    #pragma unroll
    for (int mi=0;mi<4;mi++)
    #pragma unroll
    for (int ni=0;ni<4;ni++)
    #pragma unroll
    for (int r=0;r<4;r++) {
        int row = m0 + mt + mi*16 + lq*4 + r;
        int col = n0 + nt0 + ni*16 + lr;
        out[(size_t)row*DM + col] = acc[mi][ni][r] + bo[col];
    }
}

// ---------------------------------------------------------------------------
extern "C" void kernel_launch(void* const* d_in, const int* in_sizes, int n_in,
                              void* d_out, int out_size, void* d_ws, size_t ws_size,
                              hipStream_t stream)
{
    const float* Q  = (const float*)d_in[0];
    const float* K  = (const float*)d_in[1];
    const float* V  = (const float*)d_in[2];
    const float* Wq = (const float*)d_in[3];
    const float* Wk = (const float*)d_in[4];
    const float* Wv = (const float*)d_in[5];
    const float* Wo = (const float*)d_in[6];
    const float* bo = (const float*)d_in[7];
    float* out = (float*)d_out;

    bf16* ws = (bf16*)d_ws;
    const size_t NTOK = (size_t)BATCH*SEQ*DM;   // 4,194,304 elements
    bf16* q_s  = ws;
    bf16* k_s  = ws + NTOK;
    bf16* vt_s = ws + 2*NTOK;
    bf16* ao   = ws + 3*NTOK;                   // 32 MB of ws total

    qkv_proj_kernel<<<dim3(8,32,3), 256, 0, stream>>>(Q,K,V,Wq,Wk,Wv,q_s,k_s,vt_s);
    attn_kernel<<<dim3(SEQ/32, BATCH*NH), 128, 0, stream>>>(q_s,k_s,vt_s, out + NTOK, ao);
    out_proj_kernel<<<dim3(8,32), 256, 0, stream>>>(ao,Wo,bo,out);
}

// Round 2
// 815.532 us; speedup vs baseline: 1.4061x; 1.1937x over previous
//
#include <hip/hip_runtime.h>
#include <hip/hip_bf16.h>

#define SEQ 2048
#define BATCH 2
#define NH 16
#define DK 64
#define DM 1024

typedef __bf16 bf16;
typedef __bf16 bf16x8 __attribute__((ext_vector_type(8)));
typedef float f32x4 __attribute__((ext_vector_type(4)));
typedef short s16x4 __attribute__((ext_vector_type(4)));

#define MFMA16(a,b,c) __builtin_amdgcn_mfma_f32_16x16x32_bf16(a,b,c,0,0,0)
#define NEG_BIG (-1.0e30f)

// async global->LDS, 16B per lane. LDS dest must be linear (base + lane*16).
#define GLL16(gsrc, ldst) __builtin_amdgcn_global_load_lds( \
    (const __attribute__((address_space(1))) void*)(gsrc), \
    (__attribute__((address_space(3))) void*)(ldst), 16, 0, 0)

__device__ __forceinline__ bf16x8 ld8(const bf16* p){ return *(const bf16x8*)p; }

// Fragment from chunk-swizzled [128][32] bf16 LDS tile (chunk = 16B = 8 elems).
__device__ __forceinline__ bf16x8 frag_bf16lds(const bf16* Ls, int row, int lq){
    int c = lq ^ (row&3);
    return *(const bf16x8*)((const char*)Ls + row*64 + c*16);
}

// Fragment from chunk-swizzled [128][32] f32 LDS tile, cvt to bf16 (out_proj B).
__device__ __forceinline__ bf16x8 frag_f32lds(const float* Ls, int row, int lq){
    int c0 = ((lq<<1)    ) ^ (row&7);
    int c1 = ((lq<<1) | 1) ^ (row&7);
    const float* p = Ls + row*32;
    f32x4 a = *(const f32x4*)(p + c0*4);
    f32x4 b = *(const f32x4*)(p + c1*4);
    bf16x8 r;
    #pragma unroll
    for (int i=0;i<4;i++){ r[i] = (bf16)a[i]; r[i+4] = (bf16)b[i]; }
    return r;
}

// ---------------------------------------------------------------------------
// f32 -> bf16 pre-conversion of Q,K,V,Wq,Wk,Wv (scratch in attn-out region,
// which is dead until attn_kernel overwrites it).
// ---------------------------------------------------------------------------
__global__ __launch_bounds__(256) void cvt_kernel(
    const float* __restrict__ Q,  const float* __restrict__ K,  const float* __restrict__ V,
    const float* __restrict__ Wq, const float* __restrict__ Wk, const float* __restrict__ Wv,
    bf16* __restrict__ Qb, bf16* __restrict__ Kb, bf16* __restrict__ Vb,
    bf16* __restrict__ Wqb, bf16* __restrict__ Wkb, bf16* __restrict__ Wvb)
{
    const int a = blockIdx.y;
    const float* src = (a==0)?Q:(a==1)?K:(a==2)?V:(a==3)?Wq:(a==4)?Wk:Wv;
    bf16* dst        = (a==0)?Qb:(a==1)?Kb:(a==2)?Vb:(a==3)?Wqb:(a==4)?Wkb:Wvb;
    const int n4 = (a<3) ? (BATCH*SEQ*DM)/4 : (DM*DM)/4;
    for (int i = blockIdx.x*256 + threadIdx.x; i < n4; i += gridDim.x*256){
        f32x4 v = ((const f32x4*)src)[i];
        bf16 o[4];
        #pragma unroll
        for (int j=0;j<4;j++) o[j] = (bf16)v[j];
        ((s16x4*)dst)[i] = *(const s16x4*)o;
    }
}

// ---------------------------------------------------------------------------
// QKV projection, pure bf16 (m97 structure): C = X @ W^T, 128x128 tile,
// BK=32, 4 waves, global_load_lds(16B) staging, swizzled ds_read_b128.
// z=0 -> q_s [B,H,S,dk]; z=1 -> k_s; z=2 -> vt_s [B,H,dk,S]
// ---------------------------------------------------------------------------
__global__ __launch_bounds__(256) void qkv_proj_kernel(
    const bf16* __restrict__ Qb, const bf16* __restrict__ Kb, const bf16* __restrict__ Vb,
    const bf16* __restrict__ Wqb, const bf16* __restrict__ Wkb, const bf16* __restrict__ Wvb,
    bf16* __restrict__ q_s, bf16* __restrict__ k_s, bf16* __restrict__ vt_s)
{
    __shared__ __align__(16) bf16 As[128*32];
    __shared__ __align__(16) bf16 Bs[128*32];
    const int z = blockIdx.z;
    const bf16* X = (z==0) ? Qb  : (z==1) ? Kb  : Vb;
    const bf16* W = (z==0) ? Wqb : (z==1) ? Wkb : Wvb;
    bf16* out     = (z==0) ? q_s : (z==1) ? k_s : vt_s;

    const int tid  = threadIdx.x;
    const int lane = tid & 63;
    const int w    = tid >> 6;
    const int lr = lane & 15, lq = lane >> 4;
    const int mt  = (w>>1)*64;
    const int nt0 = (w&1)*64;
    const int m0 = blockIdx.y*128;
    const int n0 = blockIdx.x*128;

    f32x4 acc[4][4] = {};
    for (int k0 = 0; k0 < DM; k0 += 32) {
        if (k0) __syncthreads();
        #pragma unroll
        for (int i=0;i<2;i++){
            int ci  = i*256 + tid;             // 16B chunk id, 0..511
            int row = ci >> 2, ch = ci & 3;
            int gc  = (ch ^ (row&3)) << 3;     // inverse-swizzled src col (elems)
            GLL16(X + (size_t)(m0+row)*DM + k0 + gc, (char*)As + ci*16);
            GLL16(W + (size_t)(n0+row)*DM + k0 + gc, (char*)Bs + ci*16);
        }
        __syncthreads();
        bf16x8 af[4], bfr[4];
        #pragma unroll
        for (int mi=0;mi<4;mi++) af[mi]  = frag_bf16lds(As, mt  + mi*16 + lr, lq);
        #pragma unroll
        for (int ni=0;ni<4;ni++) bfr[ni] = frag_bf16lds(Bs, nt0 + ni*16 + lr, lq);
        #pragma unroll
        for (int mi=0;mi<4;mi++)
            #pragma unroll
            for (int ni=0;ni<4;ni++)
                acc[mi][ni] = MFMA16(af[mi], bfr[ni], acc[mi][ni]);
    }

    if (z == 2) {
        #pragma unroll
        for (int mi=0;mi<4;mi++)
        #pragma unroll
        for (int ni=0;ni<4;ni++){
            int row = m0 + mt + mi*16 + lq*4;          // first of 4 tokens
            int col = n0 + nt0 + ni*16 + lr;
            int b = row >> 11, s = row & (SEQ-1);
            int h = col >> 6,  dd = col & 63;
            bf16 pk[4];
            #pragma unroll
            for (int r=0;r<4;r++) pk[r] = (bf16)acc[mi][ni][r];
            *(s16x4*)&out[((size_t)((b*NH + h)*DK + dd))*SEQ + s] = *(const s16x4*)pk;
        }
    } else {
        #pragma unroll
        for (int mi=0;mi<4;mi++)
        #pragma unroll
        for (int ni=0;ni<4;ni++)
        #pragma unroll
        for (int r=0;r<4;r++) {
            int row = m0 + mt + mi*16 + lq*4 + r;
            int col = n0 + nt0 + ni*16 + lr;
            int b = row >> 11, s = row & (SEQ-1);
            int h = col >> 6,  dd = col & 63;
            out[((size_t)(b*NH + h))*SEQ*DK + (size_t)s*DK + dd] = (bf16)acc[mi][ni][r];
        }
    }
}

// ---------------------------------------------------------------------------
// Attention. Block = 2 independent waves; wave 0 -> q-tile blockIdx.y,
// wave 1 -> q-tile 127-blockIdx.y  => every block has identical total work
// (causal-balance pairing; defeats the degenerate CU assignment).
// Grid (32 bh, 64 pairs): id mod 8 = bh mod 8 -> 4 heads per XCD, K+V = 2MB
// fits per-XCD L2. Max-free two-pass softmax (scores bounded).
// Pass 1: per-lane partial exp-sums, ONE shuffle reduce at the end; K-tile
// register double-buffer. Pass 2: V fragments batch-hoisted before exp/store.
// ---------------------------------------------------------------------------
__device__ __forceinline__ void load_ktile(const bf16* __restrict__ kp,
                                           int kt, int lr, int lq, bf16x8* kf){
    #pragma unroll
    for (int ks=0;ks<2;ks++)
        #pragma unroll
        for (int nt=0;nt<4;nt++)
            kf[ks*4+nt] = ld8(kp + (size_t)(kt*64 + nt*16 + lr)*DK + ks*32 + lq*8);
}

__device__ __forceinline__ void mfma_scores(const bf16x8* qf, const bf16x8* kf, f32x4* s){
    const f32x4 z4 = {0.f,0.f,0.f,0.f};
    #pragma unroll
    for (int nt=0;nt<4;nt++) s[nt] = z4;
    #pragma unroll
    for (int ks=0;ks<2;ks++)
        #pragma unroll
        for (int nt=0;nt<4;nt++)
            s[nt] = MFMA16(qf[ks], kf[ks*4+nt], s[nt]);
}

__global__ __launch_bounds__(128,4) void attn_kernel(
    const bf16* __restrict__ q_s, const bf16* __restrict__ k_s,
    const bf16* __restrict__ vt_s,
    float* __restrict__ attn_out, bf16* __restrict__ ao)
{
    __shared__ __align__(16) bf16 P[2][16][72];
    const int bh = blockIdx.x;
    const int lane = threadIdx.x & 63, w = threadIdx.x >> 6;
    const int lr = lane & 15, lq = lane >> 4;
    const int qtile = w ? (127 - (int)blockIdx.y) : (int)blockIdx.y;
    const int qw0   = qtile*16;
    const int ktmax = qw0 >> 6;                   // diagonal 64-key tile

    const bf16* qp = q_s  + (size_t)bh*SEQ*DK;
    const bf16* kp = k_s  + (size_t)bh*SEQ*DK;
    const bf16* vp = vt_s + (size_t)bh*DK*SEQ;
    float* ab = attn_out + (size_t)bh*SEQ*SEQ;

    bf16x8 qf[2];
    qf[0] = ld8(qp + (size_t)(qw0+lr)*DK + lq*8);
    qf[1] = ld8(qp + (size_t)(qw0+lr)*DK + 32 + lq*8);

    // ---- pass 1: per-lane partial exp-sums; K double-buffered ----
    float lsum[4] = {0.f,0.f,0.f,0.f};
    bf16x8 kf[8];
    load_ktile(kp, 0, lr, lq, kf);
    for (int kt=0; kt<ktmax; kt++) {              // full (unmasked) tiles
        bf16x8 kn[8];
        load_ktile(kp, kt+1, lr, lq, kn);         // prefetch next tile
        f32x4 s[4];
        mfma_scores(qf, kf, s);
        #pragma unroll
        for (int nt=0;nt<4;nt++)
            #pragma unroll
            for (int r=0;r<4;r++)
                lsum[r] += __expf(s[nt][r]*0.125f);
        #pragma unroll
        for (int i=0;i<8;i++) kf[i] = kn[i];
    }
    {   // diagonal tile (masked)
        f32x4 s[4];
        mfma_scores(qf, kf, s);
        #pragma unroll
        for (int nt=0;nt<4;nt++)
            #pragma unroll
            for (int r=0;r<4;r++){
                float v = s[nt][r]*0.125f;
                if ((ktmax*64 + nt*16 + lr) > (qw0 + lq*4 + r)) v = NEG_BIG;
                lsum[r] += __expf(v);
            }
    }
    float inv_l[4];
    #pragma unroll
    for (int r=0;r<4;r++){
        float t = lsum[r];
        t += __shfl_xor(t,1); t += __shfl_xor(t,2);
        t += __shfl_xor(t,4); t += __shfl_xor(t,8);
        inv_l[r] = 1.0f / t;
    }

    // ---- pass 2: normalized attn stores + O accumulate ----
    f32x4 o[4] = {};
    for (int kt=0; kt<=ktmax; kt++) {
        load_ktile(kp, kt, lr, lq, kf);
        f32x4 s[4];
        mfma_scores(qf, kf, s);
        bf16x8 vf[8];                              // batch-hoisted V loads:
        #pragma unroll                             // in flight under exp/stores
        for (int ks=0;ks<2;ks++)
            #pragma unroll
            for (int nt=0;nt<4;nt++)
                vf[ks*4+nt] = ld8(vp + (size_t)(nt*16+lr)*SEQ + kt*64 + ks*32 + lq*8);
        if (kt < ktmax) {
            #pragma unroll
            for (int nt=0;nt<4;nt++)
                #pragma unroll
                for (int r=0;r<4;r++){
                    float p = __expf(s[nt][r]*0.125f) * inv_l[r];
                    ab[(size_t)(qw0 + lq*4 + r)*SEQ + kt*64 + nt*16 + lr] = p;
                    P[w][lq*4+r][nt*16+lr] = (bf16)p;
                }
        } else {
            #pragma unroll
            for (int nt=0;nt<4;nt++)
                #pragma unroll
                for (int r=0;r<4;r++){
                    float v = s[nt][r]*0.125f;
                    if ((kt*64 + nt*16 + lr) > (qw0 + lq*4 + r)) v = NEG_BIG;
                    float p = __expf(v) * inv_l[r];
                    ab[(size_t)(qw0 + lq*4 + r)*SEQ + kt*64 + nt*16 + lr] = p;
                    P[w][lq*4+r][nt*16+lr] = (bf16)p;
                }
        }
        __asm__ __volatile__("" ::: "memory");     // keep LDS writes before reads
        #pragma unroll
        for (int ks=0;ks<2;ks++){
            bf16x8 pf = *(const bf16x8*)(&P[w][lr][ks*32 + lq*8]);  // A-layout
            #pragma unroll
            for (int nt=0;nt<4;nt++)
                o[nt] = MFMA16(pf, vf[ks*4+nt], o[nt]);
        }
    }

    const int b = bh >> 4, h = bh & 15;
    #pragma unroll
    for (int nt=0;nt<4;nt++)
        #pragma unroll
        for (int r=0;r<4;r++){
            int qrow = qw0 + lq*4 + r;
            ao[(size_t)(b*SEQ + qrow)*DM + h*64 + nt*16 + lr] = (bf16)o[nt][r];
        }

    // ---- zero-fill this wave's strictly-upper attn columns ----
    int cstart = (ktmax+1)*64;
    if (cstart < SEQ) {
        const f32x4 z4 = {0.f,0.f,0.f,0.f};
        float* rp = ab + (size_t)(qw0 + (lane>>2))*SEQ;   // 4 lanes per row
        for (int c4 = (cstart>>2) + (lane&3); c4 < (SEQ>>2); c4 += 4)
            *(f32x4*)(rp + c4*4) = z4;
    }
}

// ---------------------------------------------------------------------------
// Output projection: out = AO @ Wo^T + bo. AO bf16, Wo f32 (staged + cvt).
// ---------------------------------------------------------------------------
__global__ __launch_bounds__(256) void out_proj_kernel(
    const bf16* __restrict__ Xa, const float* __restrict__ Wo,
    const float* __restrict__ bo, float* __restrict__ out)
{
    __shared__ __align__(16) bf16  Asb[128*32];
    __shared__ __align__(16) float Bs [128*32];
    const int tid  = threadIdx.x;
    const int lane = tid & 63;
    const int w    = tid >> 6;
    const int lr = lane & 15, lq = lane >> 4;
    const int mt  = (w>>1)*64;
    const int nt0 = (w&1)*64;
    const int m0 = blockIdx.y*128;
    const int n0 = blockIdx.x*128;

    f32x4 acc[4][4] = {};
    for (int k0 = 0; k0 < DM; k0 += 32) {
        if (k0) __syncthreads();
        #pragma unroll
        for (int i=0;i<2;i++){
            int ci  = i*256 + tid;
            int row = ci >> 2, ch = ci & 3;
            GLL16(Xa + (size_t)(m0+row)*DM + k0 + ((ch ^ (row&3))<<3),
                  (char*)Asb + ci*16);
        }
        #pragma unroll
        for (int i=0;i<4;i++){
            int ci  = i*256 + tid;
            int row = ci >> 3, ch = ci & 7;
            GLL16(Wo + (size_t)(n0+row)*DM + k0 + ((ch ^ (row&7))<<2),
                  (char*)Bs + ci*16);
        }
        __syncthreads();
        bf16x8 af[4], bfr[4];
        #pragma unroll
        for (int mi=0;mi<4;mi++) af[mi]  = frag_bf16lds(Asb, mt  + mi*16 + lr, lq);
        #pragma unroll
        for (int ni=0;ni<4;ni++) bfr[ni] = frag_f32lds (Bs,  nt0 + ni*16 + lr, lq);
        #pragma unroll
        for (int mi=0;mi<4;mi++)
            #pragma unroll
            for (int ni=0;ni<4;ni++)
                acc[mi][ni] = MFMA16(af[mi], bfr[ni], acc[mi][ni]);
    }
    #pragma unroll
    for (int mi=0;mi<4;mi++)
    #pragma unroll
    for (int ni=0;ni<4;ni++)
    #pragma unroll
    for (int r=0;r<4;r++) {
        int row = m0 + mt + mi*16 + lq*4 + r;
        int col = n0 + nt0 + ni*16 + lr;
        out[(size_t)row*DM + col] = acc[mi][ni][r] + bo[col];
    }
}

// ---------------------------------------------------------------------------
extern "C" void kernel_launch(void* const* d_in, const int* in_sizes, int n_in,
                              void* d_out, int out_size, void* d_ws, size_t ws_size,
                              hipStream_t stream)
{
    const float* Q  = (const float*)d_in[0];
    const float* K  = (const float*)d_in[1];
    const float* V  = (const float*)d_in[2];
    const float* Wq = (const float*)d_in[3];
    const float* Wk = (const float*)d_in[4];
    const float* Wv = (const float*)d_in[5];
    const float* Wo = (const float*)d_in[6];
    const float* bo = (const float*)d_in[7];
    float* out = (float*)d_out;

    bf16* ws = (bf16*)d_ws;
    const size_t NTOK = (size_t)BATCH*SEQ*DM;   // 4,194,304 elements
    bf16* q_s  = ws;
    bf16* k_s  = ws + NTOK;
    bf16* vt_s = ws + 2*NTOK;
    bf16* ao   = ws + 3*NTOK;                   // 32 MB of ws total

    // bf16 scratch lives in the attn-output region of d_out (512 MB), which is
    // dead until attn_kernel fully overwrites it (stream-ordered after qkv).
    float* ab  = out + NTOK;
    bf16* Qb   = (bf16*)ab;
    bf16* Kb   = Qb + NTOK;
    bf16* Vb   = Qb + 2*NTOK;
    bf16* Wqb  = Qb + 3*NTOK;
    bf16* Wkb  = Wqb + (size_t)DM*DM;
    bf16* Wvb  = Wqb + 2*(size_t)DM*DM;         // total 30 MB << 512 MB

    cvt_kernel<<<dim3(256,6), 256, 0, stream>>>(Q,K,V,Wq,Wk,Wv, Qb,Kb,Vb,Wqb,Wkb,Wvb);
    qkv_proj_kernel<<<dim3(8,32,3), 256, 0, stream>>>(Qb,Kb,Vb,Wqb,Wkb,Wvb, q_s,k_s,vt_s);
    attn_kernel<<<dim3(32,64), 128, 0, stream>>>(q_s,k_s,vt_s, ab, ao);
    out_proj_kernel<<<dim3(8,32), 256, 0, stream>>>(ao,Wo,bo,out);
}

// Round 3
// 763.055 us; speedup vs baseline: 1.5028x; 1.0688x over previous
//
#include <hip/hip_runtime.h>
#include <hip/hip_bf16.h>

#define SEQ 2048
#define BATCH 2
#define NH 16
#define DK 64
#define DM 1024

typedef __bf16 bf16;
typedef __bf16 bf16x8 __attribute__((ext_vector_type(8)));
typedef float f32x4 __attribute__((ext_vector_type(4)));
typedef short s16x4 __attribute__((ext_vector_type(4)));

#define MFMA16(a,b,c) __builtin_amdgcn_mfma_f32_16x16x32_bf16(a,b,c,0,0,0)
#define NEG_BIG (-1.0e30f)

// async global->LDS, 16B per lane. LDS dest must be linear (base + lane*16).
#define GLL16(gsrc, ldst) __builtin_amdgcn_global_load_lds( \
    (const __attribute__((address_space(1))) void*)(gsrc), \
    (__attribute__((address_space(3))) void*)(ldst), 16, 0, 0)

__device__ __forceinline__ bf16x8 ld8(const bf16* p){ return *(const bf16x8*)p; }

// Fragment from chunk-swizzled [128][32] bf16 LDS tile (chunk = 16B = 8 elems).
__device__ __forceinline__ bf16x8 frag_bf16lds(const bf16* Ls, int row, int lq){
    int c = lq ^ (row&3);
    return *(const bf16x8*)((const char*)Ls + row*64 + c*16);
}

// ---------------------------------------------------------------------------
// f32 -> bf16 pre-conversion of Q,K,V,Wq,Wk,Wv (scratch in attn-out region,
// dead until attn_kernel overwrites it).
// ---------------------------------------------------------------------------
__global__ __launch_bounds__(256) void cvt_kernel(
    const float* __restrict__ Q,  const float* __restrict__ K,  const float* __restrict__ V,
    const float* __restrict__ Wq, const float* __restrict__ Wk, const float* __restrict__ Wv,
    bf16* __restrict__ Qb, bf16* __restrict__ Kb, bf16* __restrict__ Vb,
    bf16* __restrict__ Wqb, bf16* __restrict__ Wkb, bf16* __restrict__ Wvb)
{
    const int a = blockIdx.y;
    const float* src = (a==0)?Q:(a==1)?K:(a==2)?V:(a==3)?Wq:(a==4)?Wk:Wv;
    bf16* dst        = (a==0)?Qb:(a==1)?Kb:(a==2)?Vb:(a==3)?Wqb:(a==4)?Wkb:Wvb;
    const int n4 = (a<3) ? (BATCH*SEQ*DM)/4 : (DM*DM)/4;
    for (int i = blockIdx.x*256 + threadIdx.x; i < n4; i += gridDim.x*256){
        f32x4 v = ((const f32x4*)src)[i];
        bf16 o[4];
        #pragma unroll
        for (int j=0;j<4;j++) o[j] = (bf16)v[j];
        ((s16x4*)dst)[i] = *(const s16x4*)o;
    }
}

// Wo -> bf16, runs AFTER attn (writes into q_s, dead by then).
__global__ __launch_bounds__(256) void cvtW_kernel(
    const float* __restrict__ W, bf16* __restrict__ Wb)
{
    const int n4 = (DM*DM)/4;
    for (int i = blockIdx.x*256 + threadIdx.x; i < n4; i += gridDim.x*256){
        f32x4 v = ((const f32x4*)W)[i];
        bf16 o[4];
        #pragma unroll
        for (int j=0;j<4;j++) o[j] = (bf16)v[j];
        ((s16x4*)Wb)[i] = *(const s16x4*)o;
    }
}

// ---------------------------------------------------------------------------
// Pure-bf16 128x128 GEMM tile body (m97 structure), shared by qkv / out_proj.
// C = X @ W^T, both inputs [*,1024] bf16 K-contiguous.
// ---------------------------------------------------------------------------
__device__ __forceinline__ void gemm_tile_bf16(
    const bf16* __restrict__ X, const bf16* __restrict__ W,
    bf16* As, bf16* Bs, int m0, int n0, int tid, int mt, int nt0,
    int lr, int lq, f32x4 acc[4][4])
{
    for (int k0 = 0; k0 < DM; k0 += 32) {
        if (k0) __syncthreads();
        #pragma unroll
        for (int i=0;i<2;i++){
            int ci  = i*256 + tid;             // 16B chunk id, 0..511
            int row = ci >> 2, ch = ci & 3;
            int gc  = (ch ^ (row&3)) << 3;     // inverse-swizzled src col (elems)
            GLL16(X + (size_t)(m0+row)*DM + k0 + gc, (char*)As + ci*16);
            GLL16(W + (size_t)(n0+row)*DM + k0 + gc, (char*)Bs + ci*16);
        }
        __syncthreads();
        bf16x8 af[4], bfr[4];
        #pragma unroll
        for (int mi=0;mi<4;mi++) af[mi]  = frag_bf16lds(As, mt  + mi*16 + lr, lq);
        #pragma unroll
        for (int ni=0;ni<4;ni++) bfr[ni] = frag_bf16lds(Bs, nt0 + ni*16 + lr, lq);
        #pragma unroll
        for (int mi=0;mi<4;mi++)
            #pragma unroll
            for (int ni=0;ni<4;ni++)
                acc[mi][ni] = MFMA16(af[mi], bfr[ni], acc[mi][ni]);
    }
}

// ---------------------------------------------------------------------------
// QKV projection. z=0 -> q_s [B,H,S,dk]; z=1 -> k_s; z=2 -> vt_s [B,H,dk,S]
// ---------------------------------------------------------------------------
__global__ __launch_bounds__(256) void qkv_proj_kernel(
    const bf16* __restrict__ Qb, const bf16* __restrict__ Kb, const bf16* __restrict__ Vb,
    const bf16* __restrict__ Wqb, const bf16* __restrict__ Wkb, const bf16* __restrict__ Wvb,
    bf16* __restrict__ q_s, bf16* __restrict__ k_s, bf16* __restrict__ vt_s)
{
    __shared__ __align__(16) bf16 As[128*32];
    __shared__ __align__(16) bf16 Bs[128*32];
    const int z = blockIdx.z;
    const bf16* X = (z==0) ? Qb  : (z==1) ? Kb  : Vb;
    const bf16* W = (z==0) ? Wqb : (z==1) ? Wkb : Wvb;
    bf16* out     = (z==0) ? q_s : (z==1) ? k_s : vt_s;

    const int tid  = threadIdx.x;
    const int lane = tid & 63;
    const int w    = tid >> 6;
    const int lr = lane & 15, lq = lane >> 4;
    const int mt  = (w>>1)*64;
    const int nt0 = (w&1)*64;
    const int m0 = blockIdx.y*128;
    const int n0 = blockIdx.x*128;

    f32x4 acc[4][4] = {};
    gemm_tile_bf16(X, W, As, Bs, m0, n0, tid, mt, nt0, lr, lq, acc);

    if (z == 2) {
        #pragma unroll
        for (int mi=0;mi<4;mi++)
        #pragma unroll
        for (int ni=0;ni<4;ni++){
            int row = m0 + mt + mi*16 + lq*4;          // first of 4 tokens
            int col = n0 + nt0 + ni*16 + lr;
            int b = row >> 11, s = row & (SEQ-1);
            int h = col >> 6,  dd = col & 63;
            bf16 pk[4];
            #pragma unroll
            for (int r=0;r<4;r++) pk[r] = (bf16)acc[mi][ni][r];
            *(s16x4*)&out[((size_t)((b*NH + h)*DK + dd))*SEQ + s] = *(const s16x4*)pk;
        }
    } else {
        #pragma unroll
        for (int mi=0;mi<4;mi++)
        #pragma unroll
        for (int ni=0;ni<4;ni++)
        #pragma unroll
        for (int r=0;r<4;r++) {
            int row = m0 + mt + mi*16 + lq*4 + r;
            int col = n0 + nt0 + ni*16 + lr;
            int b = row >> 11, s = row & (SEQ-1);
            int h = col >> 6,  dd = col & 63;
            out[((size_t)(b*NH + h))*SEQ*DK + (size_t)s*DK + dd] = (bf16)acc[mi][ni][r];
        }
    }
}

// ---------------------------------------------------------------------------
// Attention. 32 queries per wave (2x16-row fragments): 8 K-loads + 8 V-loads
// per 64-key tile now feed 16 MFMA (2x the arithmetic intensity of r2).
// Block = 2 waves on paired q-tiles (y, 63-y) -> identical work per block.
// Grid (32 bh, 32): id mod 8 = bh mod 8 -> 4 heads/XCD, K+V fits L2.
// Max-free two-pass softmax (scores bounded). P via XOR-swizzled LDS
// (linear 128B rows, byte ^= (row&7)<<4 -> conflict-free b128 reads).
// ---------------------------------------------------------------------------
__device__ __forceinline__ void load_ktile(const bf16* __restrict__ kp,
                                           int kt, int lr, int lq, bf16x8* kf){
    #pragma unroll
    for (int ks=0;ks<2;ks++)
        #pragma unroll
        for (int nt=0;nt<4;nt++)
            kf[ks*4+nt] = ld8(kp + (size_t)(kt*64 + nt*16 + lr)*DK + ks*32 + lq*8);
}

__device__ __forceinline__ void mfma_scores(const bf16x8* qf, const bf16x8* kf, f32x4* s){
    const f32x4 z4 = {0.f,0.f,0.f,0.f};
    #pragma unroll
    for (int nt=0;nt<4;nt++) s[nt] = z4;
    #pragma unroll
    for (int ks=0;ks<2;ks++)
        #pragma unroll
        for (int nt=0;nt<4;nt++)
            s[nt] = MFMA16(qf[ks], kf[ks*4+nt], s[nt]);
}

__global__ __launch_bounds__(128,2) void attn_kernel(
    const bf16* __restrict__ q_s, const bf16* __restrict__ k_s,
    const bf16* __restrict__ vt_s,
    float* __restrict__ attn_out, bf16* __restrict__ ao)
{
    __shared__ __align__(16) bf16 P[2][32][64];   // XOR-swizzled, 128B rows
    const int bh = blockIdx.x;
    const int lane = threadIdx.x & 63, w = threadIdx.x >> 6;
    const int lr = lane & 15, lq = lane >> 4;
    const int qtile = w ? (63 - (int)blockIdx.y) : (int)blockIdx.y;
    const int qw0   = qtile*32;                   // 32-query tile
    const int ktmax = (qw0 + 31) >> 6;            // diagonal 64-key tile

    const bf16* qp = q_s  + (size_t)bh*SEQ*DK;
    const bf16* kp = k_s  + (size_t)bh*SEQ*DK;
    const bf16* vp = vt_s + (size_t)bh*DK*SEQ;
    float* ab = attn_out + (size_t)bh*SEQ*SEQ;
    char* Pw = (char*)&P[w][0][0];

    bf16x8 qf[2][2];
    #pragma unroll
    for (int qi=0;qi<2;qi++)
        #pragma unroll
        for (int ks=0;ks<2;ks++)
            qf[qi][ks] = ld8(qp + (size_t)(qw0+qi*16+lr)*DK + ks*32 + lq*8);

    // ---- pass 1: per-lane partial exp-sums; K double-buffered ----
    float lsum[2][4] = {};
    bf16x8 kf[8];
    load_ktile(kp, 0, lr, lq, kf);
    for (int kt=0; kt<ktmax; kt++) {              // full (unmasked) tiles
        bf16x8 kn[8];
        load_ktile(kp, kt+1, lr, lq, kn);         // prefetch next tile
        #pragma unroll
        for (int qi=0;qi<2;qi++){
            f32x4 s[4];
            mfma_scores(qf[qi], kf, s);
            #pragma unroll
            for (int nt=0;nt<4;nt++)
                #pragma unroll
                for (int r=0;r<4;r++)
                    lsum[qi][r] += __expf(s[nt][r]*0.125f);
        }
        #pragma unroll
        for (int i=0;i<8;i++) kf[i] = kn[i];
    }
    {   // diagonal tile (masked)
        #pragma unroll
        for (int qi=0;qi<2;qi++){
            f32x4 s[4];
            mfma_scores(qf[qi], kf, s);
            #pragma unroll
            for (int nt=0;nt<4;nt++)
                #pragma unroll
                for (int r=0;r<4;r++){
                    float v = s[nt][r]*0.125f;
                    if ((ktmax*64 + nt*16 + lr) > (qw0 + qi*16 + lq*4 + r)) v = NEG_BIG;
                    lsum[qi][r] += __expf(v);
                }
        }
    }
    float inv_l[2][4];
    #pragma unroll
    for (int qi=0;qi<2;qi++)
        #pragma unroll
        for (int r=0;r<4;r++){
            float t = lsum[qi][r];
            t += __shfl_xor(t,1); t += __shfl_xor(t,2);
            t += __shfl_xor(t,4); t += __shfl_xor(t,8);
            inv_l[qi][r] = 1.0f / t;
        }

    // ---- pass 2: normalized attn stores + O accumulate ----
    f32x4 o[2][4] = {};
    for (int kt=0; kt<=ktmax; kt++) {
        load_ktile(kp, kt, lr, lq, kf);
        bf16x8 vf[8];                              // hoisted V loads
        #pragma unroll
        for (int ks=0;ks<2;ks++)
            #pragma unroll
            for (int nt=0;nt<4;nt++)
                vf[ks*4+nt] = ld8(vp + (size_t)(nt*16+lr)*SEQ + kt*64 + ks*32 + lq*8);
        #pragma unroll
        for (int qi=0;qi<2;qi++){
            f32x4 s[4];
            mfma_scores(qf[qi], kf, s);
            if (kt < ktmax) {
                #pragma unroll
                for (int nt=0;nt<4;nt++)
                    #pragma unroll
                    for (int r=0;r<4;r++){
                        float p = __expf(s[nt][r]*0.125f) * inv_l[qi][r];
                        int row = qi*16 + lq*4 + r, col = nt*16 + lr;
                        ab[(size_t)(qw0 + row)*SEQ + kt*64 + col] = p;
                        *(bf16*)(Pw + row*128 + ((col*2) ^ ((row&7)<<4))) = (bf16)p;
                    }
            } else {
                #pragma unroll
                for (int nt=0;nt<4;nt++)
                    #pragma unroll
                    for (int r=0;r<4;r++){
                        float v = s[nt][r]*0.125f;
                        if ((kt*64 + nt*16 + lr) > (qw0 + qi*16 + lq*4 + r)) v = NEG_BIG;
                        float p = __expf(v) * inv_l[qi][r];
                        int row = qi*16 + lq*4 + r, col = nt*16 + lr;
                        ab[(size_t)(qw0 + row)*SEQ + kt*64 + col] = p;
                        *(bf16*)(Pw + row*128 + ((col*2) ^ ((row&7)<<4))) = (bf16)p;
                    }
            }
        }
        __asm__ __volatile__("" ::: "memory");     // keep LDS writes before reads
        #pragma unroll
        for (int qi=0;qi<2;qi++)
            #pragma unroll
            for (int ks=0;ks<2;ks++){
                int row = qi*16 + lr;
                bf16x8 pf = *(const bf16x8*)(Pw + row*128
                                + ((ks*64 + lq*16) ^ ((row&7)<<4)));  // A-layout
                #pragma unroll
                for (int nt=0;nt<4;nt++)
                    o[qi][nt] = MFMA16(pf, vf[ks*4+nt], o[qi][nt]);
            }
    }

    const int b = bh >> 4, h = bh & 15;
    #pragma unroll
    for (int qi=0;qi<2;qi++)
        #pragma unroll
        for (int nt=0;nt<4;nt++)
            #pragma unroll
            for (int r=0;r<4;r++){
                int qrow = qw0 + qi*16 + lq*4 + r;
                ao[(size_t)(b*SEQ + qrow)*DM + h*64 + nt*16 + lr] = (bf16)o[qi][nt][r];
            }

    // ---- zero-fill this wave's strictly-upper attn columns (32 rows) ----
    int cstart = (ktmax+1)*64;
    if (cstart < SEQ) {
        const f32x4 z4 = {0.f,0.f,0.f,0.f};
        float* rp = ab + (size_t)(qw0 + (lane>>1))*SEQ;   // 2 lanes per row
        for (int c4 = (cstart>>2) + (lane&1); c4 < (SEQ>>2); c4 += 2)
            *(f32x4*)(rp + c4*4) = z4;
    }
}

// ---------------------------------------------------------------------------
// Output projection, pure bf16: out = AO @ Wob^T + bo (out f32).
// ---------------------------------------------------------------------------
__global__ __launch_bounds__(256) void out_proj_kernel(
    const bf16* __restrict__ Xa, const bf16* __restrict__ Wob,
    const float* __restrict__ bo, float* __restrict__ out)
{
    __shared__ __align__(16) bf16 As[128*32];
    __shared__ __align__(16) bf16 Bs[128*32];
    const int tid  = threadIdx.x;
    const int lane = tid & 63;
    const int w    = tid >> 6;
    const int lr = lane & 15, lq = lane >> 4;
    const int mt  = (w>>1)*64;
    const int nt0 = (w&1)*64;
    const int m0 = blockIdx.y*128;
    const int n0 = blockIdx.x*128;

    f32x4 acc[4][4] = {};
    gemm_tile_bf16(Xa, Wob, As, Bs, m0, n0, tid, mt, nt0, lr, lq, acc);

    #pragma unroll
    for (int mi=0;mi<4;mi++)
    #pragma unroll
    for (int ni=0;ni<4;ni++)
    #pragma unroll
    for (int r=0;r<4;r++) {
        int row = m0 + mt + mi*16 + lq*4 + r;
        int col = n0 + nt0 + ni*16 + lr;
        out[(size_t)row*DM + col] = acc[mi][ni][r] + bo[col];
    }
}

// ---------------------------------------------------------------------------
extern "C" void kernel_launch(void* const* d_in, const int* in_sizes, int n_in,
                              void* d_out, int out_size, void* d_ws, size_t ws_size,
                              hipStream_t stream)
{
    const float* Q  = (const float*)d_in[0];
    const float* K  = (const float*)d_in[1];
    const float* V  = (const float*)d_in[2];
    const float* Wq = (const float*)d_in[3];
    const float* Wk = (const float*)d_in[4];
    const float* Wv = (const float*)d_in[5];
    const float* Wo = (const float*)d_in[6];
    const float* bo = (const float*)d_in[7];
    float* out = (float*)d_out;

    bf16* ws = (bf16*)d_ws;
    const size_t NTOK = (size_t)BATCH*SEQ*DM;   // 4,194,304 elements
    bf16* q_s  = ws;
    bf16* k_s  = ws + NTOK;
    bf16* vt_s = ws + 2*NTOK;
    bf16* ao   = ws + 3*NTOK;                   // 32 MB of ws total

    // bf16 scratch lives in the attn-output region of d_out (512 MB), which is
    // dead until attn_kernel fully overwrites it (stream-ordered after qkv).
    float* ab  = out + NTOK;
    bf16* Qb   = (bf16*)ab;
    bf16* Kb   = Qb + NTOK;
    bf16* Vb   = Qb + 2*NTOK;
    bf16* Wqb  = Qb + 3*NTOK;
    bf16* Wkb  = Wqb + (size_t)DM*DM;
    bf16* Wvb  = Wqb + 2*(size_t)DM*DM;         // total 30 MB << 512 MB

    // Wob lives in q_s, which is dead after attn_kernel.
    bf16* Wob  = q_s;

    cvt_kernel<<<dim3(256,6), 256, 0, stream>>>(Q,K,V,Wq,Wk,Wv, Qb,Kb,Vb,Wqb,Wkb,Wvb);
    qkv_proj_kernel<<<dim3(8,32,3), 256, 0, stream>>>(Qb,Kb,Vb,Wqb,Wkb,Wvb, q_s,k_s,vt_s);
    attn_kernel<<<dim3(32,32), 128, 0, stream>>>(q_s,k_s,vt_s, ab, ao);
    cvtW_kernel<<<dim3(128), 256, 0, stream>>>(Wo, Wob);
    out_proj_kernel<<<dim3(8,32), 256, 0, stream>>>(ao,Wob,bo,out);
}